// Round 19
// baseline (948.456 us; speedup 1.0000x reference)
//
#include <hip/hip_runtime.h>
#include <hip/hip_bf16.h>
#include <math.h>

// ---------------- problem constants ----------------
#define N_BATCH 2
#define HH 50
#define WW 84
#define NPIX (HH*WW)           // 4200
#define KA (NPIX*9)            // 37800
#define N_PRE 6000
#define N_POST 300
#define NMS_T 0.7f
#define NEGV (-1e9f)
#define NWORDS 94              // ceil(6000/64)

// d_out offsets (floats)
#define OFF_LOCS   0
#define OFF_SCORES (N_BATCH*KA*4)                  // 302400
#define OFF_ROIS   (OFF_SCORES + N_BATCH*KA*2)     // 453600
#define OFF_RIDX   (OFF_ROIS + N_BATCH*N_POST*4)   // 456000
#define OFF_ANCH   (OFF_RIDX + N_BATCH*N_POST)     // 456600

// ws offsets (bytes), all 16B aligned
#define WS_HID    0ull          // p0 partial (17203200 B)
#define WS_ROI    17505600ull
#define WS_ITEMS  18715200ull
#define WS_SITEMS 19320000ull
#define WS_SBOX   19416000ull
#define WS_MASK   19608000ull   // 9,024,000 B -> ends 28632000
#define WS_DIAG   28632000ull   // 96000 B -> ends 28728000
#define WS_ZERO   28728000ull   // 256 B zero pad source for DMA
#define WS_PEXT   28824000ull   // extra conv partials p1..p3 (17203200 B each)
#define WS_WT     WS_ITEMS      // wT3 parked over items region during conv
#define WS_BINS   28152384ull   // u32[2][65536], after wT3 end; sequential use
#define PART_BYTES 17203200ull

typedef unsigned long long u64;
typedef unsigned u32;

#define AS1 __attribute__((address_space(1)))
#define AS3 __attribute__((address_space(3)))

// ---------------- init: weight shuffle (64-oc chunks) + bins/zero-pad -------
// wT3[(t2*8+ocb)*1152 + ((kx*3+ky)*2+icl)*64 + ocl] =
//   w[(ocb*64+ocl)*4608 + (t2*2+icl)*9 + ky*3 + kx]
__global__ __launch_bounds__(64) void k_init(const float* __restrict__ w,
    float* __restrict__ wT3, u32* __restrict__ bins, float* __restrict__ zbuf) {
  __shared__ float ls[64][19];
  const int t2 = blockIdx.x, ocb = blockIdx.y;
  const int tid = threadIdx.x;
  if (ocb == 8) {
    int base = t2 * 64 + tid;
#pragma unroll
    for (int k = 0; k < 8; k++) bins[base + k * 16384] = 0u;
    if (t2 == 0) zbuf[tid] = 0.f;
    return;
  }
#pragma unroll
  for (int j = 0; j < 18; j++) {
    int idx = tid + j * 64;            // 0..1151
    int oc = idx / 18, r = idx % 18;
    ls[oc][r] = w[(size_t)(ocb * 64 + oc) * 4608 + t2 * 18 + r];
  }
  __syncthreads();
  float* outp = wT3 + (size_t)(t2 * 8 + ocb) * 1152;
#pragma unroll
  for (int j = 0; j < 18; j++) {
    int idx = tid + j * 64;
    int q = idx / 64, oc = idx % 64;
    int kxky = q >> 1, icl = q & 1;
    int kx = kxky / 3, ky = kxky % 3;
    outp[idx] = ls[oc][icl * 9 + ky * 3 + kx];
  }
}

// ---------------- conv1 3x3 512->512 (partial over ics_per channels) --------
// R16 body (4 oc x 21 px, FMA-bound LDS ratio 0.86) + R17's occupancy request
// launch_bounds(64,4) (VGPR cap 128, measured 120 -> fits). Counted vmcnt(27).
// FMA order (ic,ky,kx,oc,px) identical -> bit-exact.
#define IC_T 2
__global__ __launch_bounds__(64, 4) void k_conv1(const float* __restrict__ x,
    const float* __restrict__ wT3, const float* __restrict__ zsrc,
    float* __restrict__ p0, float* __restrict__ p1,
    float* __restrict__ p2, float* __restrict__ p3,
    int ics_per) {
  const int icq = blockIdx.x >> 1;   // z fastest -> XCD-local working set
  const int n   = blockIdx.x & 1;
  const int ocb = blockIdx.y;        // 0..7 (64 oc)
  const int row = blockIdx.z;        // 0..49
  const int tid = threadIdx.x;  // 0..63
  const int g   = tid & 3;      // px group (21 px)
  const int ocl = tid >> 2;     // 0..15 (4 oc each)
  const int ics0 = icq * ics_per;
  const int tiles = ics_per / IC_T;

  __shared__ __align__(16) float lx[2][IC_T * 3 * 96];   // 4.6KB
  __shared__ __align__(16) float lw[2][IC_T * 9 * 64];   // 9.2KB

  const float* xg = x + ((size_t)n * 512 + ics0) * NPIX;

  int goff[9];
#pragma unroll
  for (int j = 0; j < 9; j++) {
    int idx = tid + j * 64;
    int ic = idx / 288; int rem = idx % 288;
    int rr = rem / 96;  int rem2 = rem % 96;
    int g2 = rem2 / 24; int q = rem2 % 24;
    int grow = row - 1 + rr;
    int gcol = g2 * 21 - 1 + q;
    bool v = ((unsigned)grow < 50u) && ((unsigned)gcol < 84u);
    goff[j] = v ? (ic * NPIX + grow * 84 + gcol) : -1;
  }

  float acc[4][21];
#pragma unroll
  for (int i = 0; i < 4; i++)
#pragma unroll
    for (int p = 0; p < 21; p++) acc[i][p] = 0.f;

  const float* wt0 = wT3 + ((size_t)(ics0 >> 1) * 8 + ocb) * 1152 + tid;

  // prologue: issue tile 0 DMAs into buffer 0 (27 outstanding)
#pragma unroll
  for (int j = 0; j < 9; j++) {
    const float* gp = (goff[j] >= 0) ? (xg + goff[j]) : zsrc;
    __builtin_amdgcn_global_load_lds((const AS1 void*)gp,
                                     (AS3 void*)&lx[0][j * 64], 4, 0, 0);
  }
#pragma unroll
  for (int j = 0; j < 18; j++)
    __builtin_amdgcn_global_load_lds((const AS1 void*)(wt0 + j * 64),
                                     (AS3 void*)&lw[0][j * 64], 4, 0, 0);

  for (int t = 0; t < tiles; t++) {
    const int cur = t & 1;
    if (t + 1 < tiles) {
      const int nxt = cur ^ 1;
      const int xadv = (t + 1) * IC_T * NPIX;
      const float* wtn = wt0 + (size_t)(t + 1) * 9216;
#pragma unroll
      for (int j = 0; j < 9; j++) {
        const float* gp = (goff[j] >= 0) ? (xg + goff[j] + xadv) : zsrc;
        __builtin_amdgcn_global_load_lds((const AS1 void*)gp,
                                         (AS3 void*)&lx[nxt][j * 64], 4, 0, 0);
      }
#pragma unroll
      for (int j = 0; j < 18; j++)
        __builtin_amdgcn_global_load_lds((const AS1 void*)(wtn + j * 64),
                                         (AS3 void*)&lw[nxt][j * 64], 4, 0, 0);
      asm volatile("s_waitcnt vmcnt(27)" ::: "memory");  // cur done, nxt in flight
    } else {
      asm volatile("s_waitcnt vmcnt(0)" ::: "memory");
    }

#pragma unroll
    for (int icl = 0; icl < IC_T; icl++) {
#pragma unroll
      for (int ky = 0; ky < 3; ky++) {
        float xv[24];
        const float* lp = &lx[cur][icl * 288 + ky * 96 + g * 24];
#pragma unroll
        for (int v4 = 0; v4 < 6; v4++) {
          float4 f = *(const float4*)&lp[v4 * 4];
          xv[v4 * 4 + 0] = f.x; xv[v4 * 4 + 1] = f.y;
          xv[v4 * 4 + 2] = f.z; xv[v4 * 4 + 3] = f.w;
        }
#pragma unroll
        for (int kx = 0; kx < 3; kx++) {
          float4 wv = *(const float4*)&lw[cur][((kx * 3 + ky) * IC_T + icl) * 64 + ocl * 4];
          float wa[4] = {wv.x, wv.y, wv.z, wv.w};
#pragma unroll
          for (int i = 0; i < 4; i++)
#pragma unroll
            for (int p = 0; p < 21; p++)
              acc[i][p] = fmaf(wa[i], xv[p + kx], acc[i][p]);
        }
      }
    }
  }

  {
    float* hp = (icq == 0) ? p0 : (icq == 1) ? p1 : (icq == 2) ? p2 : p3;
    int oc = ocb * 64 + ocl * 4;
#pragma unroll
    for (int i = 0; i < 4; i++) {
      float* op = &hp[(size_t)(n * 512 + oc + i) * NPIX + row * 84 + g * 21];
#pragma unroll
      for (int p = 0; p < 21; p++) op[p] = acc[i][p];
    }
  }
}

// ---------------- heads (1x1) + combine + softmax + anchors + roi-prep + hist16
// 263 blocks x 256 thr = 32 px x 8 output-groups (7 outputs each, 54 used).
__global__ __launch_bounds__(256) void k_head(
    const float* __restrict__ p0, const float* __restrict__ p1,
    const float* __restrict__ p2, const float* __restrict__ p3, int nsplit,
    const float* __restrict__ bias,
    const float* __restrict__ sw, const float* __restrict__ sb,
    const float* __restrict__ lww, const float* __restrict__ lb,
    const int* __restrict__ ihp, const int* __restrict__ iwp,
    float* __restrict__ out, float4* __restrict__ roi, u64* __restrict__ items,
    u32* __restrict__ bins) {
  const int tid = threadIdx.x;
  const int q = tid >> 5;            // 0..7
  const int pxl = tid & 31;
  const int P = blockIdx.x * 32 + pxl;
  const bool valid = P < N_BATCH * NPIX;
  const int n = P / NPIX, p = P - n * NPIX;
  const int o0 = q * 7;
  __shared__ float xt[32][32];       // 4KB
  __shared__ float wt[32][56];       // 7KB
  __shared__ float lall[32][57];     // 7.3KB (57: bank-conflict pad)

  float acc[7];
#pragma unroll
  for (int o = 0; o < 7; o++) acc[o] = 0.f;

  for (int c0 = 0; c0 < 512; c0 += 32) {
#pragma unroll
    for (int j = 0; j < 4; j++) {
      int idx = tid + j * 256;
      int c = idx >> 5, lp = idx & 31;
      int PP = blockIdx.x * 32 + lp;
      float v = 0.f;
      if (PP < N_BATCH * NPIX) {
        int nn = PP / NPIX, pp = PP - nn * NPIX;
        size_t off = (size_t)(nn * 512 + c0 + c) * NPIX + pp;
        v = p0[off];
        if (nsplit > 1) v += p1[off];
        if (nsplit > 2) { v += p2[off]; v += p3[off]; }
        v += bias[c0 + c];
        v = v > 0.f ? v : 0.f;
      }
      xt[c][lp] = v;
    }
    for (int i = tid; i < 32 * 54; i += 256) {
      int c = i / 54, o = i % 54;
      wt[c][o] = (o < 18) ? sw[o * 512 + c0 + c] : lww[(o - 18) * 512 + c0 + c];
    }
    __syncthreads();
#pragma unroll 4
    for (int c = 0; c < 32; c++) {
      float xv = xt[c][pxl];
      const float* wp = &wt[c][o0];
#pragma unroll
      for (int o = 0; o < 7; o++) acc[o] = fmaf(xv, wp[o], acc[o]);
    }
    __syncthreads();
  }

  if (valid) {
#pragma unroll
    for (int j = 0; j < 7; j++) {
      int o = o0 + j;
      if (o < 54) {
        float v = acc[j] + ((o < 18) ? sb[o] : lb[o - 18]);
        lall[pxl][o] = v;
        if (o < 18) out[OFF_SCORES + ((size_t)n * KA + (size_t)p * 9) * 2 + o] = v;
        else        out[OFF_LOCS + ((size_t)n * KA + (size_t)p * 9) * 4 + (o - 18)] = v;
      }
    }
  }
  __syncthreads();

  if (valid && q == 0) {   // lanes 0..31 of wave 0
    const int pi = p / WW, pj = p - pi * WW;
    const float sy = (float)(pi * 16), sx = (float)(pj * 16);
    const float imh = (float)ihp[0], imw = (float)iwp[0];
    const u32 neg16 = (~__float_as_uint(NEGV)) >> 16;
#pragma unroll
    for (int a = 0; a < 9; a++) {
      int ri = a / 3, si = a % 3;
      double ratio = (ri == 0) ? 0.5 : ((ri == 1) ? 1.0 : 2.0);
      double scale = (si == 0) ? 8.0 : ((si == 1) ? 16.0 : 32.0);
      double hh = 16.0 * scale * sqrt(ratio);
      double ww = 16.0 * scale * sqrt(1.0 / ratio);
      float ay1 = (float)(8.0 - hh * 0.5), ax1 = (float)(8.0 - ww * 0.5);
      float ay2 = (float)(8.0 + hh * 0.5), ax2 = (float)(8.0 + ww * 0.5);
      float4 A = make_float4(sy + ay1, sx + ax1, sy + ay2, sx + ax2);
      int k = p * 9 + a;
      if (n == 0) ((float4*)out)[OFF_ANCH / 4 + k] = A;
      float r0 = lall[pxl][2 * a], r1 = lall[pxl][2 * a + 1];
      float m = fmaxf(r0, r1);
      float e0 = expf(r0 - m), e1 = expf(r1 - m);
      float fgv = e1 / (e0 + e1);
      float Lx = lall[pxl][18 + 4 * a],     Ly = lall[pxl][18 + 4 * a + 1];
      float Lz = lall[pxl][18 + 4 * a + 2], Lw = lall[pxl][18 + 4 * a + 3];
      float h = A.z - A.x, w = A.w - A.y;
      float yc = A.x + 0.5f * h, xc = A.y + 0.5f * w;
      float cy = Lx * h + yc, cx = Ly * w + xc;
      float nh = expf(Lz) * h, nw = expf(Lw) * w;
      float y1 = cy - 0.5f * nh, x1 = cx - 0.5f * nw;
      float y2 = cy + 0.5f * nh, x2 = cx + 0.5f * nw;
      y1 = fminf(fmaxf(y1, 0.f), imh); y2 = fminf(fmaxf(y2, 0.f), imh);
      x1 = fminf(fmaxf(x1, 0.f), imw); x2 = fminf(fmaxf(x2, 0.f), imw);
      bool ok = ((y2 - y1) >= 16.f) && ((x2 - x1) >= 16.f);
      float sc = ok ? fgv : NEGV;
      u32 u = __float_as_uint(sc);
      u32 key = (u & 0x80000000u) ? ~u : (u | 0x80000000u);
      roi[(size_t)n * KA + k] = make_float4(y1, x1, y2, x2);
      items[(size_t)n * KA + k] = ((u64)key << 32) | (u32)(~(u32)k);
      if (ok) {
        atomicAdd(&bins[(u32)n * 65536u + (key >> 16)], 1u);
      }
      u64 bal0 = __ballot(!ok && n == 0);
      u64 bal1 = __ballot(!ok && n == 1);
      if (pxl == 0) {
        u32 c0n = (u32)__popcll(bal0), c1n = (u32)__popcll(bal1);
        if (c0n) atomicAdd(&bins[neg16], c0n);
        if (c1n) atomicAdd(&bins[65536u + neg16], c1n);
      }
    }
  }
}

// ---------------- per-batch: kth from bins16 + compact + bitonic sort -------
__global__ __launch_bounds__(1024) void k_select2(const u64* __restrict__ items,
    const float4* __restrict__ roi, const u32* __restrict__ bins16,
    u64* __restrict__ sitems, float4* __restrict__ sbox) {
  const int b = blockIdx.x;
  const int tid = threadIdx.x;
  const int lane = tid & 63;
  const u64* it = items + (size_t)b * KA;
  __shared__ u64 arr[8192];          // 64KB
  __shared__ u32 psA[1024], psB[1024];
  __shared__ u32 sh_kth, sh_cnt;
  if (tid == 0) sh_cnt = 0;
  const u32* bins = bins16 + (size_t)b * 65536;

  u32 s = 0;
#pragma unroll 4
  for (int j = 0; j < 16; j++) {
    uint4 v = ((const uint4*)bins)[tid * 16 + j];
    s += v.x + v.y + v.z + v.w;
  }
  psA[tid] = s;
  __syncthreads();
  u32* src = psA; u32* dst = psB;
  for (int off = 1; off < 1024; off <<= 1) {
    u32 v = src[tid] + ((tid + off < 1024) ? src[tid + off] : 0u);
    __syncthreads();
    dst[tid] = v;
    __syncthreads();
    u32* tmp = src; src = dst; dst = tmp;
  }
  {
    u32 Sc = src[tid];
    u32 Sn = (tid == 1023) ? 0u : src[tid + 1];
    if (Sc >= N_PRE && Sn < N_PRE) {
      u32 needq = N_PRE - Sn;
      u32 cum = 0; int jj = 63;
      for (; jj > 0; jj--) {
        cum += bins[tid * 64 + jj];
        if (cum >= needq) break;
      }
      sh_kth = ((u32)(tid * 64 + jj)) << 16;
    }
  }
  __syncthreads();
  u32 kth = sh_kth;

  for (int i0 = 0; i0 < KA; i0 += 1024) {
    int i = i0 + tid;
    u64 v = (i < KA) ? it[i] : 0ull;
    bool sel = (i < KA) && ((u32)(v >> 32) >= kth);
    u64 bal = __ballot(sel);
    u32 cnt = (u32)__popcll(bal);
    u32 base = 0;
    if (lane == 0 && cnt) base = atomicAdd(&sh_cnt, cnt);
    base = (u32)__shfl((int)base, 0, 64);
    if (sel) {
      u32 pos = base + (u32)__popcll(bal & ((1ull << lane) - 1ull));
      if (pos < 8192) arr[pos] = v;
    }
  }
  __syncthreads();
  u32 T = sh_cnt; if (T > 8192) T = 8192;
  for (int i = (int)T + tid; i < 8192; i += 1024) arr[i] = 0ull;

  for (u32 k = 2; k <= 8192; k <<= 1) {
    for (u32 j = k >> 1; j > 0; j >>= 1) {
      __syncthreads();
#pragma unroll 4
      for (u32 m = tid; m < 4096; m += 1024) {
        u32 mm = m & (j - 1);
        u32 i = ((m - mm) << 1) + mm;
        u32 l = i + j;
        u64 a = arr[i], c = arr[l];
        bool dir = ((i & k) == 0);
        if ((a < c) == dir) { arr[i] = c; arr[l] = a; }
      }
    }
  }
  __syncthreads();
  for (int i = tid; i < N_PRE; i += 1024) {
    u64 v = arr[i];
    sitems[(size_t)b * N_PRE + i] = v;
    u32 kk = ~(u32)(v & 0xffffffffull);
    float4 bx = make_float4(0, 0, 0, 0);
    if (kk < KA) bx = roi[(size_t)b * KA + kk];
    sbox[(size_t)b * N_PRE + i] = bx;
  }
}

// ---------------- NMS suppression bitmask (triangle-linear grid) ------------
__global__ __launch_bounds__(64) void k_mask(const float4* __restrict__ sbox,
    u64* __restrict__ mask, u64* __restrict__ diag) {
  const int m = blockIdx.x;          // 0..4464 upper-triangle linear
  const int b = blockIdx.y;
  int rb = (int)(94.5 - sqrt(94.5 * 94.5 - 2.0 * (double)m));
  while (94 * rb - rb * (rb - 1) / 2 > m) rb--;
  while (94 * (rb + 1) - (rb + 1) * rb / 2 <= m) rb++;
  const int cb = rb + (m - (94 * rb - rb * (rb - 1) / 2));
  const int tid = threadIdx.x;
  __shared__ float4 cbx[64];
  __shared__ float carea[64];
  int col0 = cb * 64;
  int c = col0 + tid;
  float4 v = (c < N_PRE) ? sbox[(size_t)b * N_PRE + c] : make_float4(0, 0, 0, 0);
  cbx[tid] = v;
  carea[tid] = (v.z - v.x) * (v.w - v.y);
  __syncthreads();
  int row = rb * 64 + tid;
  if (row >= N_PRE) return;
  float4 r = sbox[(size_t)b * N_PRE + row];
  float rarea = (r.z - r.x) * (r.w - r.y);
  u64 word = 0ull;
  for (int j = 0; j < 64; j++) {
    int cc = col0 + j;
    if (cc > row && cc < N_PRE) {
      float4 q = cbx[j];
      float ty = fmaxf(r.x, q.x), tx = fmaxf(r.y, q.y);
      float by = fminf(r.z, q.z), bx = fminf(r.w, q.w);
      float ihh = fmaxf(by - ty, 0.f), iww = fmaxf(bx - tx, 0.f);
      float inter = ihh * iww;
      float iou = inter / (rarea + carea[j] - inter + 1e-9f);
      if (iou > NMS_T) word |= (1ull << j);
    }
  }
  mask[((size_t)b * N_PRE + row) * NWORDS + cb] = word;
  if (cb == rb) diag[(size_t)b * N_PRE + row] = word;
}

// ---------------- sequential NMS reduce (4-deep chained via diag) + outputs --
__global__ __launch_bounds__(64) void k_nms_out(const u64* __restrict__ sitems,
    const float4* __restrict__ sbox, const u64* __restrict__ mask,
    const u64* __restrict__ diag, float* __restrict__ out) {
  const int b = blockIdx.x;
  const int lane = threadIdx.x;
  __shared__ u64 remv[NWORDS];
  __shared__ u64 pre[NWORDS];
  __shared__ u64 dia[N_PRE];
  __shared__ u32 keep[N_POST];
  for (int i = lane; i < NWORDS; i += 64) { remv[i] = 0ull; pre[i] = 0ull; }
  __syncthreads();
  u32 keyneg = ~__float_as_uint(NEGV);
  for (int i = lane; i < N_PRE; i += 64) {
    dia[i] = diag[(size_t)b * N_PRE + i];
    u32 key = (u32)(sitems[(size_t)b * N_PRE + i] >> 32);
    if (key == keyneg || key == 0u)
      atomicOr(&pre[i >> 6], 1ull << (i & 63));
  }
  if (lane == 0) pre[NWORDS - 1] |= ~((1ull << (N_PRE - 64 * (NWORDS - 1))) - 1ull);
  __syncthreads();

  int kc = 0;
  for (int g = 0; g < NWORDS && kc < N_POST; g++) {
    u64 done = 0ull;
    while (kc < N_POST) {
      u64 cur = remv[g] | pre[g] | done;
      if (cur == ~0ull) break;
      int r0 = -1, r1 = -1, r2 = -1, r3 = -1; int m = 1;
      u64 c2 = cur;
      int bit = __ffsll((long long)(~c2)) - 1;
      r0 = g * 64 + bit; c2 |= (1ull << bit) | dia[r0]; done |= 1ull << bit;
      if (c2 != ~0ull && kc + 1 < N_POST) {
        bit = __ffsll((long long)(~c2)) - 1;
        r1 = g * 64 + bit; c2 |= (1ull << bit) | dia[r1]; done |= 1ull << bit; m = 2;
        if (c2 != ~0ull && kc + 2 < N_POST) {
          bit = __ffsll((long long)(~c2)) - 1;
          r2 = g * 64 + bit; c2 |= (1ull << bit) | dia[r2]; done |= 1ull << bit; m = 3;
          if (c2 != ~0ull && kc + 3 < N_POST) {
            bit = __ffsll((long long)(~c2)) - 1;
            r3 = g * 64 + bit; c2 |= (1ull << bit) | dia[r3]; done |= 1ull << bit; m = 4;
          }
        }
      }
      if (lane == 0) {
        keep[kc] = (u32)r0;
        if (m > 1) keep[kc + 1] = (u32)r1;
        if (m > 2) keep[kc + 2] = (u32)r2;
        if (m > 3) keep[kc + 3] = (u32)r3;
      }
      int j = lane >> 4, l16 = lane & 15;
      int rj = (j == 0) ? r0 : (j == 1) ? r1 : (j == 2) ? r2 : r3;
      if (j < m) {
        const u64* mrow = mask + ((size_t)b * N_PRE + rj) * NWORDS;
        int cb0 = g + l16;
        int cb1 = cb0 + 16, cb2c = cb0 + 32, cb3 = cb0 + 48;
        int cb4 = cb0 + 64, cb5 = cb0 + 80;
        u64 w0 = (cb0 < NWORDS) ? mrow[cb0] : 0ull;
        u64 w1 = (cb1 < NWORDS) ? mrow[cb1] : 0ull;
        u64 w2 = (cb2c < NWORDS) ? mrow[cb2c] : 0ull;
        u64 w3 = (cb3 < NWORDS) ? mrow[cb3] : 0ull;
        u64 w4 = (cb4 < NWORDS) ? mrow[cb4] : 0ull;
        u64 w5 = (cb5 < NWORDS) ? mrow[cb5] : 0ull;
        if (w0) atomicOr(&remv[cb0], w0);
        if (w1) atomicOr(&remv[cb1], w1);
        if (w2) atomicOr(&remv[cb2c], w2);
        if (w3) atomicOr(&remv[cb3], w3);
        if (w4) atomicOr(&remv[cb4], w4);
        if (w5) atomicOr(&remv[cb5], w5);
      }
      kc += m;
      __syncthreads();
    }
  }
  __syncthreads();
  for (int r = lane; r < N_POST; r += 64) {
    float4 bx = make_float4(0, 0, 0, 0);
    if (r < kc) bx = sbox[(size_t)b * N_PRE + keep[r]];
    ((float4*)out)[OFF_ROIS / 4 + (size_t)b * N_POST + r] = bx;
    out[OFF_RIDX + (size_t)b * N_POST + r] = (float)b;
  }
}

// ---------------- launch ----------------
extern "C" void kernel_launch(void* const* d_in, const int* in_sizes, int n_in,
                              void* d_out, int out_size, void* d_ws, size_t ws_size,
                              hipStream_t stream) {
  const float* x   = (const float*)d_in[0];
  const float* c1w = (const float*)d_in[1];
  const float* c1b = (const float*)d_in[2];
  const float* sw  = (const float*)d_in[3];
  const float* sb  = (const float*)d_in[4];
  const float* lw  = (const float*)d_in[5];
  const float* lb  = (const float*)d_in[6];
  const int* ih    = (const int*)d_in[7];
  const int* iw    = (const int*)d_in[8];
  float* out = (float*)d_out;
  char* wsb = (char*)d_ws;

  float* hid   = (float*)(wsb + WS_HID);
  float4* roi  = (float4*)(wsb + WS_ROI);
  u64* items   = (u64*)(wsb + WS_ITEMS);
  u64* sitems  = (u64*)(wsb + WS_SITEMS);
  float4* sbox = (float4*)(wsb + WS_SBOX);
  u64* maskp   = (u64*)(wsb + WS_MASK);
  u64* diagp   = (u64*)(wsb + WS_DIAG);
  u32* bins    = (u32*)(wsb + WS_BINS);
  float* zbuf  = (float*)(wsb + WS_ZERO);
  float* wT3   = (float*)(wsb + WS_WT);

  int nsplit = 1;
  if (ws_size >= WS_PEXT + 3 * PART_BYTES) nsplit = 4;
  else if (ws_size >= WS_PEXT + 1 * PART_BYTES) nsplit = 2;
  float* p1 = (nsplit > 1) ? (float*)(wsb + WS_PEXT) : hid;
  float* p2 = (nsplit > 2) ? (float*)(wsb + WS_PEXT + PART_BYTES) : hid;
  float* p3 = (nsplit > 2) ? (float*)(wsb + WS_PEXT + 2 * PART_BYTES) : hid;

  hipLaunchKernelGGL(k_init, dim3(256, 9), dim3(64), 0, stream, c1w, wT3, bins, zbuf);
  hipLaunchKernelGGL(k_conv1, dim3(2 * nsplit, 8, 50), dim3(64), 0, stream,
                     x, wT3, zbuf, hid, p1, p2, p3, 512 / nsplit);
  hipLaunchKernelGGL(k_head, dim3(263), dim3(256), 0, stream,
                     hid, p1, p2, p3, nsplit, c1b, sw, sb, lw, lb, ih, iw,
                     out, roi, items, bins);
  hipLaunchKernelGGL(k_select2, dim3(2), dim3(1024), 0, stream,
                     items, roi, bins, sitems, sbox);
  hipLaunchKernelGGL(k_mask, dim3(4465, 2), dim3(64), 0, stream, sbox, maskp, diagp);
  hipLaunchKernelGGL(k_nms_out, dim3(2), dim3(64), 0, stream, sitems, sbox, maskp, diagp, out);
}

// Round 20
// 929.512 us; speedup vs baseline: 1.0204x; 1.0204x over previous
//
#include <hip/hip_runtime.h>
#include <hip/hip_bf16.h>
#include <math.h>

// ---------------- problem constants ----------------
#define N_BATCH 2
#define HH 50
#define WW 84
#define NPIX (HH*WW)           // 4200
#define KA (NPIX*9)            // 37800
#define N_PRE 6000
#define N_POST 300
#define NMS_T 0.7f
#define NEGV (-1e9f)
#define NWORDS 94              // ceil(6000/64)

// d_out offsets (floats)
#define OFF_LOCS   0
#define OFF_SCORES (N_BATCH*KA*4)                  // 302400
#define OFF_ROIS   (OFF_SCORES + N_BATCH*KA*2)     // 453600
#define OFF_RIDX   (OFF_ROIS + N_BATCH*N_POST*4)   // 456000
#define OFF_ANCH   (OFF_RIDX + N_BATCH*N_POST)     // 456600

// ws offsets (bytes), all 16B aligned
#define WS_HID    0ull          // p0 partial (17203200 B)
#define WS_ROI    17505600ull
#define WS_ITEMS  18715200ull
#define WS_SITEMS 19320000ull
#define WS_SBOX   19416000ull
#define WS_MASK   19608000ull   // 9,024,000 B -> ends 28632000
#define WS_DIAG   28632000ull   // 96000 B -> ends 28728000
#define WS_ZERO   28728000ull   // 256 B zero pad source for DMA
#define WS_PEXT   28824000ull   // extra conv partials p1..p3 (17203200 B each)
#define WS_WT     WS_ITEMS      // wT4 parked over items region during conv
#define WS_BINS   28152384ull   // u32[2][65536], after wT4 end; sequential use
#define PART_BYTES 17203200ull

typedef unsigned long long u64;
typedef unsigned u32;

#define AS1 __attribute__((address_space(1)))
#define AS3 __attribute__((address_space(3)))

// ---------------- init: weight shuffle (32-oc chunks) + bins/zero-pad -------
// wT4[(t2*16+ocb)*576 + ((kx*3+ky)*2+icl)*32 + ocl] =
//   w[(ocb*32+ocl)*4608 + (t2*2+icl)*9 + ky*3 + kx]
__global__ __launch_bounds__(64) void k_init(const float* __restrict__ w,
    float* __restrict__ wT4, u32* __restrict__ bins, float* __restrict__ zbuf) {
  __shared__ float ls[32][19];
  const int t2 = blockIdx.x, ocb = blockIdx.y;
  const int tid = threadIdx.x;
  if (ocb == 16) {
    int base = t2 * 64 + tid;
#pragma unroll
    for (int k = 0; k < 8; k++) bins[base + k * 16384] = 0u;
    if (t2 == 0) zbuf[tid] = 0.f;
    return;
  }
#pragma unroll
  for (int j = 0; j < 9; j++) {
    int idx = tid + j * 64;            // 0..575
    int oc = idx / 18, r = idx % 18;
    ls[oc][r] = w[(size_t)(ocb * 32 + oc) * 4608 + t2 * 18 + r];
  }
  __syncthreads();
  float* outp = wT4 + (size_t)(t2 * 16 + ocb) * 576;
#pragma unroll
  for (int j = 0; j < 9; j++) {
    int idx = tid + j * 64;
    int q = idx / 32, oc = idx % 32;
    int kxky = q >> 1, icl = q & 1;
    int kx = kxky / 3, ky = kxky % 3;
    outp[idx] = ls[oc][icl * 9 + ky * 3 + kx];
  }
}

// ---------------- conv1 3x3 512->512 (partial over ics_per channels) --------
// R17 exact (best measured: 575us, occ 33%, VGPR 64): 64-thr single-wave
// block = 32 oc x 1 row; thread = 2 oc x 21 px. Async-DMA double-buffered,
// counted vmcnt(18). FMA order (ic,ky,kx,oc,px) identical -> bit-exact.
#define IC_T 2
__global__ __launch_bounds__(64, 4) void k_conv1(const float* __restrict__ x,
    const float* __restrict__ wT4, const float* __restrict__ zsrc,
    float* __restrict__ p0, float* __restrict__ p1,
    float* __restrict__ p2, float* __restrict__ p3,
    int ics_per) {
  const int icq = blockIdx.x >> 1;   // z fastest -> XCD-local working set
  const int n   = blockIdx.x & 1;
  const int ocb = blockIdx.y;        // 0..15 (32 oc)
  const int row = blockIdx.z;        // 0..49
  const int tid = threadIdx.x;  // 0..63
  const int g   = tid & 3;      // px group (21 px)
  const int ocl = tid >> 2;     // 0..15 (2 oc each)
  const int ics0 = icq * ics_per;
  const int tiles = ics_per / IC_T;

  __shared__ __align__(16) float lx[2][IC_T * 3 * 96];   // 4.6KB
  __shared__ __align__(16) float lw[2][IC_T * 9 * 32];   // 4.6KB

  const float* xg = x + ((size_t)n * 512 + ics0) * NPIX;

  int goff[9];
#pragma unroll
  for (int j = 0; j < 9; j++) {
    int idx = tid + j * 64;
    int ic = idx / 288; int rem = idx % 288;
    int rr = rem / 96;  int rem2 = rem % 96;
    int g2 = rem2 / 24; int q = rem2 % 24;
    int grow = row - 1 + rr;
    int gcol = g2 * 21 - 1 + q;
    bool v = ((unsigned)grow < 50u) && ((unsigned)gcol < 84u);
    goff[j] = v ? (ic * NPIX + grow * 84 + gcol) : -1;
  }

  float acc[2][21];
#pragma unroll
  for (int i = 0; i < 2; i++)
#pragma unroll
    for (int p = 0; p < 21; p++) acc[i][p] = 0.f;

  const float* wt0 = wT4 + ((size_t)(ics0 >> 1) * 16 + ocb) * 576 + tid;

  // prologue: issue tile 0 DMAs into buffer 0 (18 outstanding)
#pragma unroll
  for (int j = 0; j < 9; j++) {
    const float* gp = (goff[j] >= 0) ? (xg + goff[j]) : zsrc;
    __builtin_amdgcn_global_load_lds((const AS1 void*)gp,
                                     (AS3 void*)&lx[0][j * 64], 4, 0, 0);
  }
#pragma unroll
  for (int j = 0; j < 9; j++)
    __builtin_amdgcn_global_load_lds((const AS1 void*)(wt0 + j * 64),
                                     (AS3 void*)&lw[0][j * 64], 4, 0, 0);

  for (int t = 0; t < tiles; t++) {
    const int cur = t & 1;
    if (t + 1 < tiles) {
      const int nxt = cur ^ 1;
      const int xadv = (t + 1) * IC_T * NPIX;
      const float* wtn = wt0 + (size_t)(t + 1) * 9216;  // 16 blocks * 576
#pragma unroll
      for (int j = 0; j < 9; j++) {
        const float* gp = (goff[j] >= 0) ? (xg + goff[j] + xadv) : zsrc;
        __builtin_amdgcn_global_load_lds((const AS1 void*)gp,
                                         (AS3 void*)&lx[nxt][j * 64], 4, 0, 0);
      }
#pragma unroll
      for (int j = 0; j < 9; j++)
        __builtin_amdgcn_global_load_lds((const AS1 void*)(wtn + j * 64),
                                         (AS3 void*)&lw[nxt][j * 64], 4, 0, 0);
      asm volatile("s_waitcnt vmcnt(18)" ::: "memory");  // cur done, nxt in flight
    } else {
      asm volatile("s_waitcnt vmcnt(0)" ::: "memory");
    }

#pragma unroll
    for (int icl = 0; icl < IC_T; icl++) {
#pragma unroll
      for (int ky = 0; ky < 3; ky++) {
        float xv[24];
        const float* lp = &lx[cur][icl * 288 + ky * 96 + g * 24];
#pragma unroll
        for (int v4 = 0; v4 < 6; v4++) {
          float4 f = *(const float4*)&lp[v4 * 4];
          xv[v4 * 4 + 0] = f.x; xv[v4 * 4 + 1] = f.y;
          xv[v4 * 4 + 2] = f.z; xv[v4 * 4 + 3] = f.w;
        }
#pragma unroll
        for (int kx = 0; kx < 3; kx++) {
          float2 wv = *(const float2*)&lw[cur][((kx * 3 + ky) * IC_T + icl) * 32 + ocl * 2];
          float wa[2] = {wv.x, wv.y};
#pragma unroll
          for (int i = 0; i < 2; i++)
#pragma unroll
            for (int p = 0; p < 21; p++)
              acc[i][p] = fmaf(wa[i], xv[p + kx], acc[i][p]);
        }
      }
    }
  }

  {
    float* hp = (icq == 0) ? p0 : (icq == 1) ? p1 : (icq == 2) ? p2 : p3;
    int oc = ocb * 32 + ocl * 2;
#pragma unroll
    for (int i = 0; i < 2; i++) {
      float* op = &hp[(size_t)(n * 512 + oc + i) * NPIX + row * 84 + g * 21];
#pragma unroll
      for (int p = 0; p < 21; p++) op[p] = acc[i][p];
    }
  }
}

// ---------------- heads (1x1) + combine + softmax + anchors + roi-prep + hist16
// 263 blocks x 256 thr = 32 px x 8 output-groups (7 outputs each, 54 used).
__global__ __launch_bounds__(256) void k_head(
    const float* __restrict__ p0, const float* __restrict__ p1,
    const float* __restrict__ p2, const float* __restrict__ p3, int nsplit,
    const float* __restrict__ bias,
    const float* __restrict__ sw, const float* __restrict__ sb,
    const float* __restrict__ lww, const float* __restrict__ lb,
    const int* __restrict__ ihp, const int* __restrict__ iwp,
    float* __restrict__ out, float4* __restrict__ roi, u64* __restrict__ items,
    u32* __restrict__ bins) {
  const int tid = threadIdx.x;
  const int q = tid >> 5;            // 0..7
  const int pxl = tid & 31;
  const int P = blockIdx.x * 32 + pxl;
  const bool valid = P < N_BATCH * NPIX;
  const int n = P / NPIX, p = P - n * NPIX;
  const int o0 = q * 7;
  __shared__ float xt[32][32];       // 4KB
  __shared__ float wt[32][56];       // 7KB
  __shared__ float lall[32][57];     // 7.3KB (57: bank-conflict pad)

  float acc[7];
#pragma unroll
  for (int o = 0; o < 7; o++) acc[o] = 0.f;

  for (int c0 = 0; c0 < 512; c0 += 32) {
#pragma unroll
    for (int j = 0; j < 4; j++) {
      int idx = tid + j * 256;
      int c = idx >> 5, lp = idx & 31;
      int PP = blockIdx.x * 32 + lp;
      float v = 0.f;
      if (PP < N_BATCH * NPIX) {
        int nn = PP / NPIX, pp = PP - nn * NPIX;
        size_t off = (size_t)(nn * 512 + c0 + c) * NPIX + pp;
        v = p0[off];
        if (nsplit > 1) v += p1[off];
        if (nsplit > 2) { v += p2[off]; v += p3[off]; }
        v += bias[c0 + c];
        v = v > 0.f ? v : 0.f;
      }
      xt[c][lp] = v;
    }
    for (int i = tid; i < 32 * 54; i += 256) {
      int c = i / 54, o = i % 54;
      wt[c][o] = (o < 18) ? sw[o * 512 + c0 + c] : lww[(o - 18) * 512 + c0 + c];
    }
    __syncthreads();
#pragma unroll 4
    for (int c = 0; c < 32; c++) {
      float xv = xt[c][pxl];
      const float* wp = &wt[c][o0];
#pragma unroll
      for (int o = 0; o < 7; o++) acc[o] = fmaf(xv, wp[o], acc[o]);
    }
    __syncthreads();
  }

  if (valid) {
#pragma unroll
    for (int j = 0; j < 7; j++) {
      int o = o0 + j;
      if (o < 54) {
        float v = acc[j] + ((o < 18) ? sb[o] : lb[o - 18]);
        lall[pxl][o] = v;
        if (o < 18) out[OFF_SCORES + ((size_t)n * KA + (size_t)p * 9) * 2 + o] = v;
        else        out[OFF_LOCS + ((size_t)n * KA + (size_t)p * 9) * 4 + (o - 18)] = v;
      }
    }
  }
  __syncthreads();

  if (valid && q == 0) {   // lanes 0..31 of wave 0
    const int pi = p / WW, pj = p - pi * WW;
    const float sy = (float)(pi * 16), sx = (float)(pj * 16);
    const float imh = (float)ihp[0], imw = (float)iwp[0];
    const u32 neg16 = (~__float_as_uint(NEGV)) >> 16;
#pragma unroll
    for (int a = 0; a < 9; a++) {
      int ri = a / 3, si = a % 3;
      double ratio = (ri == 0) ? 0.5 : ((ri == 1) ? 1.0 : 2.0);
      double scale = (si == 0) ? 8.0 : ((si == 1) ? 16.0 : 32.0);
      double hh = 16.0 * scale * sqrt(ratio);
      double ww = 16.0 * scale * sqrt(1.0 / ratio);
      float ay1 = (float)(8.0 - hh * 0.5), ax1 = (float)(8.0 - ww * 0.5);
      float ay2 = (float)(8.0 + hh * 0.5), ax2 = (float)(8.0 + ww * 0.5);
      float4 A = make_float4(sy + ay1, sx + ax1, sy + ay2, sx + ax2);
      int k = p * 9 + a;
      if (n == 0) ((float4*)out)[OFF_ANCH / 4 + k] = A;
      float r0 = lall[pxl][2 * a], r1 = lall[pxl][2 * a + 1];
      float m = fmaxf(r0, r1);
      float e0 = expf(r0 - m), e1 = expf(r1 - m);
      float fgv = e1 / (e0 + e1);
      float Lx = lall[pxl][18 + 4 * a],     Ly = lall[pxl][18 + 4 * a + 1];
      float Lz = lall[pxl][18 + 4 * a + 2], Lw = lall[pxl][18 + 4 * a + 3];
      float h = A.z - A.x, w = A.w - A.y;
      float yc = A.x + 0.5f * h, xc = A.y + 0.5f * w;
      float cy = Lx * h + yc, cx = Ly * w + xc;
      float nh = expf(Lz) * h, nw = expf(Lw) * w;
      float y1 = cy - 0.5f * nh, x1 = cx - 0.5f * nw;
      float y2 = cy + 0.5f * nh, x2 = cx + 0.5f * nw;
      y1 = fminf(fmaxf(y1, 0.f), imh); y2 = fminf(fmaxf(y2, 0.f), imh);
      x1 = fminf(fmaxf(x1, 0.f), imw); x2 = fminf(fmaxf(x2, 0.f), imw);
      bool ok = ((y2 - y1) >= 16.f) && ((x2 - x1) >= 16.f);
      float sc = ok ? fgv : NEGV;
      u32 u = __float_as_uint(sc);
      u32 key = (u & 0x80000000u) ? ~u : (u | 0x80000000u);
      roi[(size_t)n * KA + k] = make_float4(y1, x1, y2, x2);
      items[(size_t)n * KA + k] = ((u64)key << 32) | (u32)(~(u32)k);
      if (ok) {
        atomicAdd(&bins[(u32)n * 65536u + (key >> 16)], 1u);
      }
      u64 bal0 = __ballot(!ok && n == 0);
      u64 bal1 = __ballot(!ok && n == 1);
      if (pxl == 0) {
        u32 c0n = (u32)__popcll(bal0), c1n = (u32)__popcll(bal1);
        if (c0n) atomicAdd(&bins[neg16], c0n);
        if (c1n) atomicAdd(&bins[65536u + neg16], c1n);
      }
    }
  }
}

// ---------------- per-batch: kth from bins16 + compact + hybrid bitonic -----
// Sort: within-chunk phases (j<=4) fused into registers (each thread owns 8
// aligned elements; for k>=8 dir is thread-uniform). LDS passes 91 -> 55.
// Comparison semantics identical -> identical sorted output.
__global__ __launch_bounds__(1024) void k_select2(const u64* __restrict__ items,
    const float4* __restrict__ roi, const u32* __restrict__ bins16,
    u64* __restrict__ sitems, float4* __restrict__ sbox) {
  const int b = blockIdx.x;
  const int tid = threadIdx.x;
  const int lane = tid & 63;
  const u64* it = items + (size_t)b * KA;
  __shared__ u64 arr[8192];          // 64KB
  __shared__ u32 psA[1024], psB[1024];
  __shared__ u32 sh_kth, sh_cnt;
  if (tid == 0) sh_cnt = 0;
  const u32* bins = bins16 + (size_t)b * 65536;

  u32 s = 0;
#pragma unroll 4
  for (int j = 0; j < 16; j++) {
    uint4 v = ((const uint4*)bins)[tid * 16 + j];
    s += v.x + v.y + v.z + v.w;
  }
  psA[tid] = s;
  __syncthreads();
  u32* src = psA; u32* dst = psB;
  for (int off = 1; off < 1024; off <<= 1) {
    u32 v = src[tid] + ((tid + off < 1024) ? src[tid + off] : 0u);
    __syncthreads();
    dst[tid] = v;
    __syncthreads();
    u32* tmp = src; src = dst; dst = tmp;
  }
  {
    u32 Sc = src[tid];
    u32 Sn = (tid == 1023) ? 0u : src[tid + 1];
    if (Sc >= N_PRE && Sn < N_PRE) {
      u32 needq = N_PRE - Sn;
      u32 cum = 0; int jj = 63;
      for (; jj > 0; jj--) {
        cum += bins[tid * 64 + jj];
        if (cum >= needq) break;
      }
      sh_kth = ((u32)(tid * 64 + jj)) << 16;
    }
  }
  __syncthreads();
  u32 kth = sh_kth;

  for (int i0 = 0; i0 < KA; i0 += 1024) {
    int i = i0 + tid;
    u64 v = (i < KA) ? it[i] : 0ull;
    bool sel = (i < KA) && ((u32)(v >> 32) >= kth);
    u64 bal = __ballot(sel);
    u32 cnt = (u32)__popcll(bal);
    u32 base0 = 0;
    if (lane == 0 && cnt) base0 = atomicAdd(&sh_cnt, cnt);
    base0 = (u32)__shfl((int)base0, 0, 64);
    if (sel) {
      u32 pos = base0 + (u32)__popcll(bal & ((1ull << lane) - 1ull));
      if (pos < 8192) arr[pos] = v;
    }
  }
  __syncthreads();
  u32 T = sh_cnt; if (T > 8192) T = 8192;
  for (int i = (int)T + tid; i < 8192; i += 1024) arr[i] = 0ull;
  __syncthreads();

  const int base = tid * 8;
  // stage A: k=2,4,8 (all j) fully in registers
  {
    u64 e[8];
#pragma unroll
    for (int l = 0; l < 8; l++) e[l] = arr[base + l];
    // k=2, j=1: dir = ((l&2)==0)
#pragma unroll
    for (int l = 0; l < 8; l += 2) {
      bool dir = ((l & 2) == 0);
      u64 a = e[l], c = e[l + 1];
      if ((a < c) == dir) { e[l] = c; e[l + 1] = a; }
    }
    // k=4, j=2: dir = ((l&4)==0)
#pragma unroll
    for (int l0 = 0; l0 < 8; l0 += 4)
#pragma unroll
      for (int l = l0; l < l0 + 2; l++) {
        bool dir = ((l & 4) == 0);
        u64 a = e[l], c = e[l + 2];
        if ((a < c) == dir) { e[l] = c; e[l + 2] = a; }
      }
    // k=4, j=1
#pragma unroll
    for (int l = 0; l < 8; l += 2) {
      bool dir = ((l & 4) == 0);
      u64 a = e[l], c = e[l + 1];
      if ((a < c) == dir) { e[l] = c; e[l + 1] = a; }
    }
    // k=8: dir uniform = ((base & 8)==0)
    {
      bool dir = ((base & 8) == 0);
#pragma unroll
      for (int l = 0; l < 4; l++) {
        u64 a = e[l], c = e[l + 4];
        if ((a < c) == dir) { e[l] = c; e[l + 4] = a; }
      }
#pragma unroll
      for (int l0 = 0; l0 < 8; l0 += 4)
#pragma unroll
        for (int l = l0; l < l0 + 2; l++) {
          u64 a = e[l], c = e[l + 2];
          if ((a < c) == dir) { e[l] = c; e[l + 2] = a; }
        }
#pragma unroll
      for (int l = 0; l < 8; l += 2) {
        u64 a = e[l], c = e[l + 1];
        if ((a < c) == dir) { e[l] = c; e[l + 1] = a; }
      }
    }
#pragma unroll
    for (int l = 0; l < 8; l++) arr[base + l] = e[l];
  }

  // stage B: k=16..8192; LDS passes for j>=8, fused register pass for j=4,2,1
  for (u32 k = 16; k <= 8192; k <<= 1) {
    for (u32 j = k >> 1; j >= 8; j >>= 1) {
      __syncthreads();
#pragma unroll 4
      for (u32 m = tid; m < 4096; m += 1024) {
        u32 mm = m & (j - 1);
        u32 i = ((m - mm) << 1) + mm;
        u32 l = i + j;
        u64 a = arr[i], c = arr[l];
        bool dir = ((i & k) == 0);
        if ((a < c) == dir) { arr[i] = c; arr[l] = a; }
      }
    }
    __syncthreads();
    {
      bool dir = (((u32)base & k) == 0);
      u64 e[8];
#pragma unroll
      for (int l = 0; l < 8; l++) e[l] = arr[base + l];
#pragma unroll
      for (int l = 0; l < 4; l++) {
        u64 a = e[l], c = e[l + 4];
        if ((a < c) == dir) { e[l] = c; e[l + 4] = a; }
      }
#pragma unroll
      for (int l0 = 0; l0 < 8; l0 += 4)
#pragma unroll
        for (int l = l0; l < l0 + 2; l++) {
          u64 a = e[l], c = e[l + 2];
          if ((a < c) == dir) { e[l] = c; e[l + 2] = a; }
        }
#pragma unroll
      for (int l = 0; l < 8; l += 2) {
        u64 a = e[l], c = e[l + 1];
        if ((a < c) == dir) { e[l] = c; e[l + 1] = a; }
      }
#pragma unroll
      for (int l = 0; l < 8; l++) arr[base + l] = e[l];
    }
    __syncthreads();
  }
  __syncthreads();
  for (int i = tid; i < N_PRE; i += 1024) {
    u64 v = arr[i];
    sitems[(size_t)b * N_PRE + i] = v;
    u32 kk = ~(u32)(v & 0xffffffffull);
    float4 bx = make_float4(0, 0, 0, 0);
    if (kk < KA) bx = roi[(size_t)b * KA + kk];
    sbox[(size_t)b * N_PRE + i] = bx;
  }
}

// ---------------- NMS suppression bitmask (triangle-linear grid) ------------
__global__ __launch_bounds__(64) void k_mask(const float4* __restrict__ sbox,
    u64* __restrict__ mask, u64* __restrict__ diag) {
  const int m = blockIdx.x;          // 0..4464 upper-triangle linear
  const int b = blockIdx.y;
  int rb = (int)(94.5 - sqrt(94.5 * 94.5 - 2.0 * (double)m));
  while (94 * rb - rb * (rb - 1) / 2 > m) rb--;
  while (94 * (rb + 1) - (rb + 1) * rb / 2 <= m) rb++;
  const int cb = rb + (m - (94 * rb - rb * (rb - 1) / 2));
  const int tid = threadIdx.x;
  __shared__ float4 cbx[64];
  __shared__ float carea[64];
  int col0 = cb * 64;
  int c = col0 + tid;
  float4 v = (c < N_PRE) ? sbox[(size_t)b * N_PRE + c] : make_float4(0, 0, 0, 0);
  cbx[tid] = v;
  carea[tid] = (v.z - v.x) * (v.w - v.y);
  __syncthreads();
  int row = rb * 64 + tid;
  if (row >= N_PRE) return;
  float4 r = sbox[(size_t)b * N_PRE + row];
  float rarea = (r.z - r.x) * (r.w - r.y);
  u64 word = 0ull;
  for (int j = 0; j < 64; j++) {
    int cc = col0 + j;
    if (cc > row && cc < N_PRE) {
      float4 q = cbx[j];
      float ty = fmaxf(r.x, q.x), tx = fmaxf(r.y, q.y);
      float by = fminf(r.z, q.z), bx = fminf(r.w, q.w);
      float ihh = fmaxf(by - ty, 0.f), iww = fmaxf(bx - tx, 0.f);
      float inter = ihh * iww;
      float iou = inter / (rarea + carea[j] - inter + 1e-9f);
      if (iou > NMS_T) word |= (1ull << j);
    }
  }
  mask[((size_t)b * N_PRE + row) * NWORDS + cb] = word;
  if (cb == rb) diag[(size_t)b * N_PRE + row] = word;
}

// ---------------- sequential NMS reduce (4-deep chained via diag) + outputs --
__global__ __launch_bounds__(64) void k_nms_out(const u64* __restrict__ sitems,
    const float4* __restrict__ sbox, const u64* __restrict__ mask,
    const u64* __restrict__ diag, float* __restrict__ out) {
  const int b = blockIdx.x;
  const int lane = threadIdx.x;
  __shared__ u64 remv[NWORDS];
  __shared__ u64 pre[NWORDS];
  __shared__ u64 dia[N_PRE];
  __shared__ u32 keep[N_POST];
  for (int i = lane; i < NWORDS; i += 64) { remv[i] = 0ull; pre[i] = 0ull; }
  __syncthreads();
  u32 keyneg = ~__float_as_uint(NEGV);
  for (int i = lane; i < N_PRE; i += 64) {
    dia[i] = diag[(size_t)b * N_PRE + i];
    u32 key = (u32)(sitems[(size_t)b * N_PRE + i] >> 32);
    if (key == keyneg || key == 0u)
      atomicOr(&pre[i >> 6], 1ull << (i & 63));
  }
  if (lane == 0) pre[NWORDS - 1] |= ~((1ull << (N_PRE - 64 * (NWORDS - 1))) - 1ull);
  __syncthreads();

  int kc = 0;
  for (int g = 0; g < NWORDS && kc < N_POST; g++) {
    u64 done = 0ull;
    while (kc < N_POST) {
      u64 cur = remv[g] | pre[g] | done;
      if (cur == ~0ull) break;
      int r0 = -1, r1 = -1, r2 = -1, r3 = -1; int m = 1;
      u64 c2 = cur;
      int bit = __ffsll((long long)(~c2)) - 1;
      r0 = g * 64 + bit; c2 |= (1ull << bit) | dia[r0]; done |= 1ull << bit;
      if (c2 != ~0ull && kc + 1 < N_POST) {
        bit = __ffsll((long long)(~c2)) - 1;
        r1 = g * 64 + bit; c2 |= (1ull << bit) | dia[r1]; done |= 1ull << bit; m = 2;
        if (c2 != ~0ull && kc + 2 < N_POST) {
          bit = __ffsll((long long)(~c2)) - 1;
          r2 = g * 64 + bit; c2 |= (1ull << bit) | dia[r2]; done |= 1ull << bit; m = 3;
          if (c2 != ~0ull && kc + 3 < N_POST) {
            bit = __ffsll((long long)(~c2)) - 1;
            r3 = g * 64 + bit; c2 |= (1ull << bit) | dia[r3]; done |= 1ull << bit; m = 4;
          }
        }
      }
      if (lane == 0) {
        keep[kc] = (u32)r0;
        if (m > 1) keep[kc + 1] = (u32)r1;
        if (m > 2) keep[kc + 2] = (u32)r2;
        if (m > 3) keep[kc + 3] = (u32)r3;
      }
      int j = lane >> 4, l16 = lane & 15;
      int rj = (j == 0) ? r0 : (j == 1) ? r1 : (j == 2) ? r2 : r3;
      if (j < m) {
        const u64* mrow = mask + ((size_t)b * N_PRE + rj) * NWORDS;
        int cb0 = g + l16;
        int cb1 = cb0 + 16, cb2c = cb0 + 32, cb3 = cb0 + 48;
        int cb4 = cb0 + 64, cb5 = cb0 + 80;
        u64 w0 = (cb0 < NWORDS) ? mrow[cb0] : 0ull;
        u64 w1 = (cb1 < NWORDS) ? mrow[cb1] : 0ull;
        u64 w2 = (cb2c < NWORDS) ? mrow[cb2c] : 0ull;
        u64 w3 = (cb3 < NWORDS) ? mrow[cb3] : 0ull;
        u64 w4 = (cb4 < NWORDS) ? mrow[cb4] : 0ull;
        u64 w5 = (cb5 < NWORDS) ? mrow[cb5] : 0ull;
        if (w0) atomicOr(&remv[cb0], w0);
        if (w1) atomicOr(&remv[cb1], w1);
        if (w2) atomicOr(&remv[cb2c], w2);
        if (w3) atomicOr(&remv[cb3], w3);
        if (w4) atomicOr(&remv[cb4], w4);
        if (w5) atomicOr(&remv[cb5], w5);
      }
      kc += m;
      __syncthreads();
    }
  }
  __syncthreads();
  for (int r = lane; r < N_POST; r += 64) {
    float4 bx = make_float4(0, 0, 0, 0);
    if (r < kc) bx = sbox[(size_t)b * N_PRE + keep[r]];
    ((float4*)out)[OFF_ROIS / 4 + (size_t)b * N_POST + r] = bx;
    out[OFF_RIDX + (size_t)b * N_POST + r] = (float)b;
  }
}

// ---------------- launch ----------------
extern "C" void kernel_launch(void* const* d_in, const int* in_sizes, int n_in,
                              void* d_out, int out_size, void* d_ws, size_t ws_size,
                              hipStream_t stream) {
  const float* x   = (const float*)d_in[0];
  const float* c1w = (const float*)d_in[1];
  const float* c1b = (const float*)d_in[2];
  const float* sw  = (const float*)d_in[3];
  const float* sb  = (const float*)d_in[4];
  const float* lw  = (const float*)d_in[5];
  const float* lb  = (const float*)d_in[6];
  const int* ih    = (const int*)d_in[7];
  const int* iw    = (const int*)d_in[8];
  float* out = (float*)d_out;
  char* wsb = (char*)d_ws;

  float* hid   = (float*)(wsb + WS_HID);
  float4* roi  = (float4*)(wsb + WS_ROI);
  u64* items   = (u64*)(wsb + WS_ITEMS);
  u64* sitems  = (u64*)(wsb + WS_SITEMS);
  float4* sbox = (float4*)(wsb + WS_SBOX);
  u64* maskp   = (u64*)(wsb + WS_MASK);
  u64* diagp   = (u64*)(wsb + WS_DIAG);
  u32* bins    = (u32*)(wsb + WS_BINS);
  float* zbuf  = (float*)(wsb + WS_ZERO);
  float* wT4   = (float*)(wsb + WS_WT);

  int nsplit = 1;
  if (ws_size >= WS_PEXT + 3 * PART_BYTES) nsplit = 4;
  else if (ws_size >= WS_PEXT + 1 * PART_BYTES) nsplit = 2;
  float* p1 = (nsplit > 1) ? (float*)(wsb + WS_PEXT) : hid;
  float* p2 = (nsplit > 2) ? (float*)(wsb + WS_PEXT + PART_BYTES) : hid;
  float* p3 = (nsplit > 2) ? (float*)(wsb + WS_PEXT + 2 * PART_BYTES) : hid;

  hipLaunchKernelGGL(k_init, dim3(256, 17), dim3(64), 0, stream, c1w, wT4, bins, zbuf);
  hipLaunchKernelGGL(k_conv1, dim3(2 * nsplit, 16, 50), dim3(64), 0, stream,
                     x, wT4, zbuf, hid, p1, p2, p3, 512 / nsplit);
  hipLaunchKernelGGL(k_head, dim3(263), dim3(256), 0, stream,
                     hid, p1, p2, p3, nsplit, c1b, sw, sb, lw, lb, ih, iw,
                     out, roi, items, bins);
  hipLaunchKernelGGL(k_select2, dim3(2), dim3(1024), 0, stream,
                     items, roi, bins, sitems, sbox);
  hipLaunchKernelGGL(k_mask, dim3(4465, 2), dim3(64), 0, stream, sbox, maskp, diagp);
  hipLaunchKernelGGL(k_nms_out, dim3(2), dim3(64), 0, stream, sitems, sbox, maskp, diagp, out);
}